// Round 9
// baseline (157.009 us; speedup 1.0000x reference)
//
#include <hip/hip_runtime.h>
#include <hip/hip_bf16.h>
#include <cstdint>

#define HDIM 1024
#define NT 32   // K-tiles of 32

typedef __attribute__((ext_vector_type(8))) __bf16 bf16x8;
typedef __attribute__((ext_vector_type(8))) unsigned short u16x8;
typedef __attribute__((ext_vector_type(4))) float f32x4;

static __device__ __forceinline__ unsigned short f2b(float f) {
    __hip_bfloat16 h = __float2bfloat16(f);
    return __builtin_bit_cast(unsigned short, h);
}

static __device__ __forceinline__ void barrier_fence() {
    asm volatile("" ::: "memory");
    __builtin_amdgcn_s_barrier();
    asm volatile("" ::: "memory");
}

// ---------------- weights fp32 -> bf16 (12 MB in ws) ----------------
__global__ void __launch_bounds__(256) cvt_w(
    const float* __restrict__ wih, const float* __restrict__ ur,
    const float* __restrict__ uz, const float* __restrict__ un,
    unsigned short* __restrict__ wb, unsigned short* __restrict__ urb,
    unsigned short* __restrict__ uzb, unsigned short* __restrict__ unb) {
    int b = blockIdx.x;
    const float* src; unsigned short* dst; int idx;
    if (b < 3072)       { src = wih; dst = wb;  idx = b; }
    else if (b < 4096)  { src = ur;  dst = urb; idx = b - 3072; }
    else if (b < 5120)  { src = uz;  dst = uzb; idx = b - 4096; }
    else                { src = un;  dst = unb; idx = b - 5120; }
    int i = idx * 256 + threadIdx.x;
    float4 v = ((const float4*)src)[i];
    ushort4 o;
    o.x = f2b(v.x); o.y = f2b(v.y); o.z = f2b(v.z); o.w = f2b(v.w);
    ((ushort4*)dst)[i] = o;
}

// R2 skeleton exactly (4 waves, BM=128, BN=64, 2 blocks/CU, 2-barrier dbuf,
// in-loop fp32->bf16 x/h staging -- measured free, hidden under MFMA), plus:
//  - persistent hoisted staging pointers (10 ptrs, +32 elems/tile): cuts
//    per-tile address VALU (R4 evidence: VALUBusy 29% -> ~23%)
//  - vmcnt(6): drains exactly the previous tile's 6 weight gload_lds
// LDS per buffer (ushort): xs[0,4096) hs[4096,8192) w[mi]@8192+mi*2048.
// Swizzle: 16B slot s of row r at s ^ ((r>>1)&3), both sides (conflict-free).
__global__ void __launch_bounds__(256, 2)
gru9(const float* __restrict__ hg,
     const float* __restrict__ xg32, const float* __restrict__ hg32,
     const unsigned short* __restrict__ wih,
     const unsigned short* __restrict__ ur,
     const unsigned short* __restrict__ uz,
     const unsigned short* __restrict__ un,
     const float* __restrict__ bih, const float* __restrict__ bun,
     float* __restrict__ out) {
    __shared__ __align__(16) unsigned short smem[2][20480];

    const int tid  = threadIdx.x;
    const int lane = tid & 63;
    const int wv   = tid >> 6;
    const int wm   = wv >> 1;
    const int wn   = wv & 1;
    const int lr   = lane & 15;
    const int ls   = lane >> 4;
    const int m0   = blockIdx.y * 128;
    const int n0   = blockIdx.x * 64;

    // ---- persistent staging pointers (advance +32 elements per K-tile)
    const int wr  = tid >> 2;                       // weight row 0..63
    const int wsl = (tid & 3) ^ ((tid >> 3) & 3);   // pre-swizzled source slot
    const unsigned short* pw[6];
    pw[0] = wih + (size_t)(n0 + wr) * HDIM + wsl * 8;
    pw[1] = wih + (size_t)(HDIM + n0 + wr) * HDIM + wsl * 8;
    pw[2] = wih + (size_t)(2 * HDIM + n0 + wr) * HDIM + wsl * 8;
    pw[3] = ur  + (size_t)(n0 + wr) * HDIM + wsl * 8;
    pw[4] = uz  + (size_t)(n0 + wr) * HDIM + wsl * 8;
    pw[5] = un  + (size_t)(n0 + wr) * HDIM + wsl * 8;

    const float* pgx[2];
    const float* pgh[2];
    int xsd[2];                                     // LDS write offsets (ushort)
#pragma unroll
    for (int half = 0; half < 2; ++half) {
        const int c2 = half * 256 + tid;            // 0..511
        const int r2 = c2 >> 2;                     // row 0..127
        const int sl = c2 & 3;                      // linear source slot
        const int sp = (c2 & 3) ^ ((c2 >> 3) & 3);  // swizzled LDS slot
        pgx[half] = xg32 + (size_t)(m0 + r2) * HDIM + sl * 8;
        pgh[half] = hg32 + (size_t)(m0 + r2) * HDIM + sl * 8;
        xsd[half] = r2 * 32 + sp * 8;
    }

    // loop-invariant ds_read lane offsets
    const int sel = (lr >> 1) & 3;
    const int fo  = (ls ^ sel) << 3;
    int aoff[4];
#pragma unroll
    for (int mf = 0; mf < 4; ++mf)
        aoff[mf] = (wm * 64 + mf * 16 + lr) * 32 + fo;
    const int boff0 = (wn * 32 + lr) * 32 + fo;
    const int boff1 = (wn * 32 + 16 + lr) * 32 + fo;

    f32x4 acc[4][4][2];
#pragma unroll
    for (int g = 0; g < 4; ++g)
#pragma unroll
        for (int mf = 0; mf < 4; ++mf)
#pragma unroll
            for (int nf = 0; nf < 2; ++nf)
                acc[g][mf][nf] = f32x4{0.f, 0.f, 0.f, 0.f};

    auto STAGE = [&](int bufi) {
        unsigned short* sb = &smem[bufi][0];
        // fp32 x/h loads issued FIRST (latency overlapped with glds issue)
        float4 fx[2][2], fh[2][2];
#pragma unroll
        for (int half = 0; half < 2; ++half) {
            fx[half][0] = ((const float4*)pgx[half])[0];
            fx[half][1] = ((const float4*)pgx[half])[1];
            fh[half][0] = ((const float4*)pgh[half])[0];
            fh[half][1] = ((const float4*)pgh[half])[1];
            pgx[half] += 32; pgh[half] += 32;
        }
        // 6 weight tiles via global_load_lds w16
#pragma unroll
        for (int mi = 0; mi < 6; ++mi) {
            __builtin_amdgcn_global_load_lds(
                (const __attribute__((address_space(1))) void*)pw[mi],
                (__attribute__((address_space(3))) void*)(sb + 8192 + mi * 2048 + wv * 512),
                16, 0, 0);
            pw[mi] += 32;
        }
        // convert + swizzled ds_write_b128
#pragma unroll
        for (int half = 0; half < 2; ++half) {
            u16x8 px, ph;
#pragma unroll
            for (int q = 0; q < 4; ++q) {
                px[q]     = f2b(fx[half][0][q]);
                px[q + 4] = f2b(fx[half][1][q]);
                ph[q]     = f2b(fh[half][0][q]);
                ph[q + 4] = f2b(fh[half][1][q]);
            }
            *(u16x8*)(sb + xsd[half])        = px;
            *(u16x8*)(sb + 4096 + xsd[half]) = ph;
        }
    };

    auto COMPUTE = [&](int bufi) {
        const unsigned short* sb = &smem[bufi][0];
        bf16x8 ax[4], ah[4];
#pragma unroll
        for (int mf = 0; mf < 4; ++mf) {
            ax[mf] = *(const bf16x8*)(sb + aoff[mf]);
            ah[mf] = *(const bf16x8*)(sb + 4096 + aoff[mf]);
        }
#pragma unroll
        for (int mi = 0; mi < 6; ++mi) {
            const unsigned short* wt = sb + 8192 + mi * 2048;
            bf16x8 b0 = *(const bf16x8*)(wt + boff0);
            bf16x8 b1 = *(const bf16x8*)(wt + boff1);
            const int g = (mi == 0 || mi == 3) ? 0 : (mi == 1 || mi == 4) ? 1 : (mi == 2) ? 2 : 3;
            const bf16x8* a = (mi < 3) ? ax : ah;
#pragma unroll
            for (int mf = 0; mf < 4; ++mf) {
                acc[g][mf][0] = __builtin_amdgcn_mfma_f32_16x16x32_bf16(a[mf], b0, acc[g][mf][0], 0, 0, 0);
                acc[g][mf][1] = __builtin_amdgcn_mfma_f32_16x16x32_bf16(a[mf], b1, acc[g][mf][1], 0, 0, 0);
            }
        }
    };

    // vmcnt(6): STAGE leaves 6 weight gload_lds outstanding (the fp32 reg
    // loads are force-drained inside STAGE by the ds_write dependency);
    // this drains exactly the previous tile's 6 and keeps the new 6 flying.
    auto WAITN = [&]() { asm volatile("s_waitcnt vmcnt(6) lgkmcnt(0)" ::: "memory"); };

    STAGE(0);
#pragma unroll 1
    for (int kt = 0; kt < NT - 2; kt += 2) {
        STAGE(1); WAITN(); barrier_fence();
        COMPUTE(0); barrier_fence();
        STAGE(0); WAITN(); barrier_fence();
        COMPUTE(1); barrier_fence();
    }
    STAGE(1); WAITN(); barrier_fence();
    COMPUTE(0); barrier_fence();
    asm volatile("s_waitcnt vmcnt(0) lgkmcnt(0)" ::: "memory");
    __builtin_amdgcn_s_barrier();
    asm volatile("" ::: "memory");
    COMPUTE(1);

    // epilogue: gates + output (C/D layout: col=lane&15, row=(lane>>4)*4+reg)
#pragma unroll
    for (int nf = 0; nf < 2; ++nf) {
        const int gc = n0 + wn * 32 + nf * 16 + lr;
        const float br  = bih[gc];
        const float bz  = bih[HDIM + gc];
        const float bnx = bih[2 * HDIM + gc];
        const float bn2 = bun[gc];
#pragma unroll
        for (int mf = 0; mf < 4; ++mf) {
#pragma unroll
            for (int rr = 0; rr < 4; ++rr) {
                const int gr = m0 + wm * 64 + mf * 16 + ls * 4 + rr;
                const float rv = 1.f / (1.f + __expf(-(acc[0][mf][nf][rr] + br)));
                const float zv = 1.f / (1.f + __expf(-(acc[1][mf][nf][rr] + bz)));
                const float nv = tanhf(acc[2][mf][nf][rr] + bnx + rv * (acc[3][mf][nf][rr] + bn2));
                const float hv = hg[(size_t)gr * HDIM + gc];
                out[(size_t)gr * HDIM + gc] = (1.f - zv) * nv + zv * hv;
            }
        }
    }
}

extern "C" void kernel_launch(void* const* d_in, const int* in_sizes, int n_in,
                              void* d_out, int out_size, void* d_ws, size_t ws_size,
                              hipStream_t stream) {
    const float* x   = (const float*)d_in[0];
    const float* h   = (const float*)d_in[1];
    const float* Wih = (const float*)d_in[2];
    const float* bih = (const float*)d_in[3];
    const float* Ur  = (const float*)d_in[4];
    const float* Uz  = (const float*)d_in[5];
    const float* Un  = (const float*)d_in[6];
    const float* bun = (const float*)d_in[7];
    float* out = (float*)d_out;

    unsigned short* wsp  = (unsigned short*)d_ws;
    unsigned short* wihb = wsp;                       // 6 MB
    unsigned short* urb  = wihb + 3 * 1024 * 1024;
    unsigned short* uzb  = urb + 1024 * 1024;
    unsigned short* unb  = uzb + 1024 * 1024;         // 12 MB total

    cvt_w<<<6144, 256, 0, stream>>>(Wih, Ur, Uz, Un, wihb, urb, uzb, unb);

    dim3 grid(HDIM / 64, 8192 / 128);  // (16, 64)
    gru9<<<grid, 256, 0, stream>>>(
        h, x, h, wihb, urb, uzb, unb, bih, bun, out);
}